// Round 1
// baseline (566.131 us; speedup 1.0000x reference)
//
#include <hip/hip_runtime.h>
#include <hip/hip_bf16.h>

constexpr int kB  = 16;
constexpr int kT  = 4096;
constexpr int kD  = 512;
constexpr int kC  = 10;
constexpr int kFW = 100;
constexpr int kKW = 2 * kFW + 1;   // 201

__device__ __forceinline__ float tanh_fast(float x) {
  float ax = fabsf(x);
  float z  = __expf(-2.0f * ax);
  float r  = (1.0f - z) / (1.0f + z);
  return copysignf(r, x);
}

// dec[b,d] = sum_k query[b,k] * W_dec[d,k]   (one wave per output)
__global__ void dec_kernel(const float* __restrict__ query,
                           const float* __restrict__ W_dec,
                           float* __restrict__ decb) {
  int gw   = (blockIdx.x * blockDim.x + threadIdx.x) >> 6;
  int lane = threadIdx.x & 63;
  int b = gw >> 9;            // /kD (512)
  int d = gw & (kD - 1);
  const float* q = query + (size_t)b * kD;
  const float* w = W_dec + (size_t)d * kD;
  float s = 0.f;
  for (int k = lane; k < kD; k += 64) s += q[k] * w[k];
#pragma unroll
  for (int off = 32; off > 0; off >>= 1) s += __shfl_down(s, off, 64);
  if (lane == 0) decb[gw] = s;
}

// convT[b][t][c] = sum_j att_prev[b, t+j-FW] * W_conv[c, j]  (zero padded)
__global__ void conv_kernel(const float* __restrict__ att_prev,
                            const float* __restrict__ W_conv,
                            float* __restrict__ convT) {
  __shared__ float ap[256 + 2 * kFW];   // 456
  __shared__ float wc[kC * kKW];        // 2010
  int b   = blockIdx.y;
  int t0  = blockIdx.x * 256;
  int tid = threadIdx.x;
  for (int i = tid; i < kC * kKW; i += 256) wc[i] = W_conv[i];
  for (int i = tid; i < 256 + 2 * kFW; i += 256) {
    int p = t0 - kFW + i;
    ap[i] = (p >= 0 && p < kT) ? att_prev[(size_t)b * kT + p] : 0.f;
  }
  __syncthreads();
  float acc[kC];
#pragma unroll
  for (int c = 0; c < kC; ++c) acc[c] = 0.f;
  for (int j = 0; j < kKW; ++j) {
    float a = ap[tid + j];
#pragma unroll
    for (int c = 0; c < kC; ++c) acc[c] += a * wc[c * kKW + j];
  }
  int t = t0 + tid;
  float* out = convT + ((size_t)b * kT + t) * kC;
#pragma unroll
  for (int c = 0; c < kC; ++c) out[c] = acc[c];
}

// e[b,t] += sum over this block's d-tile of w_g[d]*tanh(valueRow.W_enc[d]
//           + b_enc[d] + dec[b,d] + sum_c conv[b,t,c]*W_att[d,c])
constexpr int BM = 64, BN = 64, BK = 16;

__global__ __launch_bounds__(256) void e_kernel(
    const float* __restrict__ value, const float* __restrict__ W_enc,
    const float* __restrict__ b_enc, const float* __restrict__ decb,
    const float* __restrict__ convT, const float* __restrict__ W_att,
    const float* __restrict__ w_g, const int* __restrict__ lens,
    float* __restrict__ e_buf) {
  __shared__ float As[BK][BM + 4];   // k-major: As[k][m], row = 68 floats (16B aligned)
  __shared__ float Bs[BK][BN + 4];
  __shared__ float red[BM][17];

  int tid = threadIdx.x;
  int bx = blockIdx.x, by = blockIdx.y;
  int b  = by >> 6;              // kT/BM = 64 m-tiles per batch
  int t0 = (by & 63) * BM;
  int len = lens[b];
  if (t0 >= len) return;         // masked tile: e stays 0 (never read by softmax)
  int n0 = bx * BN;
  int rg = tid >> 4, dg = tid & 15;       // 16x16 thread grid, 4x4 microtile
  int lm = tid >> 2, lk = (tid & 3) * 4;  // staging: one float4 per thread

  const float* Aptr = value + ((size_t)(b * kT + t0) + lm) * kD + lk;
  const float* Bptr = W_enc + (size_t)(n0 + lm) * kD + lk;

  float acc[4][4] = {};

  for (int k0 = 0; k0 < kD; k0 += BK) {
    float4 a = *(const float4*)(Aptr + k0);
    float4 w = *(const float4*)(Bptr + k0);
    __syncthreads();
    As[lk + 0][lm] = a.x; As[lk + 1][lm] = a.y; As[lk + 2][lm] = a.z; As[lk + 3][lm] = a.w;
    Bs[lk + 0][lm] = w.x; Bs[lk + 1][lm] = w.y; Bs[lk + 2][lm] = w.z; Bs[lk + 3][lm] = w.w;
    __syncthreads();
#pragma unroll
    for (int k = 0; k < BK; ++k) {
      float4 av = *(const float4*)(&As[k][rg * 4]);
      float4 bv = *(const float4*)(&Bs[k][dg * 4]);
      acc[0][0] += av.x * bv.x; acc[0][1] += av.x * bv.y;
      acc[0][2] += av.x * bv.z; acc[0][3] += av.x * bv.w;
      acc[1][0] += av.y * bv.x; acc[1][1] += av.y * bv.y;
      acc[1][2] += av.y * bv.z; acc[1][3] += av.y * bv.w;
      acc[2][0] += av.z * bv.x; acc[2][1] += av.z * bv.y;
      acc[2][2] += av.z * bv.z; acc[2][3] += av.z * bv.w;
      acc[3][0] += av.w * bv.x; acc[3][1] += av.w * bv.y;
      acc[3][2] += av.w * bv.z; acc[3][3] += av.w * bv.w;
    }
  }

  // fused epilogue: bias + dec + rank-10 conv update + tanh + w_g dot
  float part[4];
  const float* cvbase = convT + (size_t)(b * kT + t0) * kC;
#pragma unroll
  for (int i = 0; i < 4; ++i) {
    int r = rg * 4 + i;
    float cv[kC];
#pragma unroll
    for (int c = 0; c < kC; ++c) cv[c] = cvbase[r * kC + c];
    float s = 0.f;
#pragma unroll
    for (int j = 0; j < 4; ++j) {
      int d = n0 + dg * 4 + j;
      float y = acc[i][j] + b_enc[d] + decb[b * kD + d];
#pragma unroll
      for (int c = 0; c < kC; ++c) y += cv[c] * W_att[d * kC + c];
      s += w_g[d] * tanh_fast(y);
    }
    part[i] = s;
  }
  __syncthreads();
#pragma unroll
  for (int i = 0; i < 4; ++i) red[rg * 4 + i][dg] = part[i];
  __syncthreads();
  if (tid < BM) {
    float s = 0.f;
#pragma unroll
    for (int q = 0; q < 16; ++q) s += red[tid][q];
    atomicAdd(&e_buf[(size_t)b * kT + t0 + tid], s);
  }
}

// masked, sharpened softmax over T per batch row (b_g dropped: shift-invariant)
__global__ void softmax_kernel(const float* __restrict__ e_buf,
                               const int* __restrict__ lens,
                               float* __restrict__ att) {
  __shared__ float sred[256];
  int b = blockIdx.x, tid = threadIdx.x;
  int len = lens[b];
  const float* e = e_buf + (size_t)b * kT;
  float m = -3.0e38f;
  for (int t = tid; t < len; t += 256) m = fmaxf(m, e[t]);
  sred[tid] = m; __syncthreads();
  for (int s = 128; s > 0; s >>= 1) {
    if (tid < s) sred[tid] = fmaxf(sred[tid], sred[tid + s]);
    __syncthreads();
  }
  m = sred[0]; __syncthreads();
  float sum = 0.f;
  for (int t = tid; t < len; t += 256) sum += __expf(2.0f * (e[t] - m));
  sred[tid] = sum; __syncthreads();
  for (int s = 128; s > 0; s >>= 1) {
    if (tid < s) sred[tid] += sred[tid + s];
    __syncthreads();
  }
  float inv = 1.0f / sred[0];
  for (int t = tid; t < kT; t += 256)
    att[(size_t)b * kT + t] = (t < len) ? __expf(2.0f * (e[t] - m)) * inv : 0.0f;
}

// context[b,d] = sum_t value[b,t,d] * att[b,t]
__global__ void context_kernel(const float* __restrict__ value,
                               const float* __restrict__ att,
                               const int* __restrict__ lens,
                               float* __restrict__ ctx) {
  int b = blockIdx.y;
  int len = lens[b];
  int t0 = blockIdx.x * 64;
  if (t0 >= len) return;
  int tmax = min(64, len - t0);
  int tid = threadIdx.x;
  const float* ap = att + (size_t)b * kT + t0;
  const float* vp = value + (size_t)(b * kT + t0) * kD + tid * 2;
  float ax = 0.f, ay = 0.f;
  for (int t = 0; t < tmax; ++t) {
    float w = ap[t];
    float2 v = *(const float2*)(vp + (size_t)t * kD);
    ax += w * v.x; ay += w * v.y;
  }
  atomicAdd(&ctx[b * kD + tid * 2],     ax);
  atomicAdd(&ctx[b * kD + tid * 2 + 1], ay);
}

extern "C" void kernel_launch(void* const* d_in, const int* in_sizes, int n_in,
                              void* d_out, int out_size, void* d_ws, size_t ws_size,
                              hipStream_t stream) {
  const float* value    = (const float*)d_in[0];   // [B,T,D]
  const float* query    = (const float*)d_in[1];   // [B,D]
  const int*   lens     = (const int*)  d_in[2];   // [B]
  const float* att_prev = (const float*)d_in[3];   // [B,T]
  const float* W_enc    = (const float*)d_in[4];   // [D,D]
  const float* b_enc    = (const float*)d_in[5];   // [D]
  const float* W_dec    = (const float*)d_in[6];   // [D,D]
  const float* W_att    = (const float*)d_in[7];   // [D,C]
  const float* W_conv   = (const float*)d_in[8];   // [C,1,201]
  const float* w_g      = (const float*)d_in[9];   // [1,D]
  // d_in[10] = b_g : unused (softmax shift-invariant)

  float* ws    = (float*)d_ws;
  float* e_buf = ws;                                 // kB*kT
  float* convT = ws + (size_t)kB * kT;               // kB*kT*kC
  float* decb  = convT + (size_t)kB * kT * kC;       // kB*kD
  float* ctx = (float*)d_out;                        // [B,D]
  float* att = ctx + (size_t)kB * kD;                // [B,T]

  hipMemsetAsync(e_buf, 0, (size_t)kB * kT * sizeof(float), stream);
  hipMemsetAsync(ctx,   0, (size_t)kB * kD * sizeof(float), stream);

  dec_kernel<<<kB * kD / 4, 256, 0, stream>>>(query, W_dec, decb);
  conv_kernel<<<dim3(kT / 256, kB), 256, 0, stream>>>(att_prev, W_conv, convT);
  e_kernel<<<dim3(kD / BN, kB * kT / BM), 256, 0, stream>>>(
      value, W_enc, b_enc, decb, convT, W_att, w_g, lens, e_buf);
  softmax_kernel<<<kB, 256, 0, stream>>>(e_buf, lens, att);
  context_kernel<<<dim3(kT / 64, kB), 256, 0, stream>>>(value, att, lens, ctx);
}

// Round 2
// 314.732 us; speedup vs baseline: 1.7988x; 1.7988x over previous
//
#include <hip/hip_runtime.h>
#include <hip/hip_bf16.h>

constexpr int kB  = 16;
constexpr int kT  = 4096;
constexpr int kD  = 512;
constexpr int kC  = 10;
constexpr int kFW = 100;
constexpr int kKW = 2 * kFW + 1;   // 201
constexpr int kKP = 544;           // padded GEMM K: 512 (W_enc) + 10 (W_att) + 22 zeros
constexpr int kCP = 16;            // padded conv channel dim

typedef __attribute__((ext_vector_type(8))) short short8_t;  // 8 bf16 (4 VGPRs)
typedef __attribute__((ext_vector_type(4))) float float4_t;  // MFMA acc

__device__ __forceinline__ float tanh_fast(float x) {
  float ax = fabsf(x);
  float z  = __expf(-2.0f * ax);
  float r  = (1.0f - z) / (1.0f + z);
  return copysignf(r, x);
}

__device__ __forceinline__ short f2bf(float x) {  // RNE f32->bf16
  unsigned u = __float_as_uint(x);
  u += 0x7fffu + ((u >> 16) & 1u);
  return (short)(u >> 16);
}

__device__ __forceinline__ void glds16(const void* g, void* l) {
  __builtin_amdgcn_global_load_lds(
      (const __attribute__((address_space(1))) void*)g,
      (__attribute__((address_space(3))) void*)l, 16, 0, 0);
}

// bias[b,d] = b_enc[d] + sum_k query[b,k] * W_dec[d,k]   (one wave per output)
__global__ void dec_bias_kernel(const float* __restrict__ query,
                                const float* __restrict__ W_dec,
                                const float* __restrict__ b_enc,
                                float* __restrict__ bias) {
  int gw   = (blockIdx.x * blockDim.x + threadIdx.x) >> 6;
  int lane = threadIdx.x & 63;
  int b = gw >> 9;
  int d = gw & (kD - 1);
  const float* q = query + (size_t)b * kD;
  const float* w = W_dec + (size_t)d * kD;
  float s = 0.f;
#pragma unroll
  for (int k0 = 0; k0 < kD; k0 += 256) {
    float4 qa = *(const float4*)(q + k0 + lane * 4);
    float4 wa = *(const float4*)(w + k0 + lane * 4);
    s += qa.x * wa.x + qa.y * wa.y + qa.z * wa.z + qa.w * wa.w;
  }
#pragma unroll
  for (int off = 32; off > 0; off >>= 1) s += __shfl_down(s, off, 64);
  if (lane == 0) bias[gw] = b_enc[d] + s;
}

// Wbf[d][544] bf16 = [W_enc[d][0:512] | W_att[d][0:10] | zeros]
__global__ void pack_w_kernel(const float* __restrict__ W_enc,
                              const float* __restrict__ W_att,
                              short* __restrict__ Wbf) {
  int d = blockIdx.x;
  for (int c = threadIdx.x; c < kKP; c += 256) {
    float v = 0.f;
    if (c < kD)            v = W_enc[(size_t)d * kD + c];
    else if (c < kD + kC)  v = W_att[(size_t)d * kC + (c - kD)];
    Wbf[(size_t)d * kKP + c] = f2bf(v);
  }
}

// convT16[b][t][0:10] = conv channels, [10:16] = 0  (fp32, padded for float4 staging)
__global__ void conv_kernel(const float* __restrict__ att_prev,
                            const float* __restrict__ W_conv,
                            float* __restrict__ convT16) {
  __shared__ float ap[256 + 2 * kFW];
  __shared__ float wc[kC * kKW];
  int b   = blockIdx.y;
  int t0  = blockIdx.x * 256;
  int tid = threadIdx.x;
  for (int i = tid; i < kC * kKW; i += 256) wc[i] = W_conv[i];
  for (int i = tid; i < 256 + 2 * kFW; i += 256) {
    int p = t0 - kFW + i;
    ap[i] = (p >= 0 && p < kT) ? att_prev[(size_t)b * kT + p] : 0.f;
  }
  __syncthreads();
  float acc[kC];
#pragma unroll
  for (int c = 0; c < kC; ++c) acc[c] = 0.f;
  for (int j = 0; j < kKW; ++j) {
    float a = ap[tid + j];
#pragma unroll
    for (int c = 0; c < kC; ++c) acc[c] += a * wc[c * kKW + j];
  }
  float* out = convT16 + ((size_t)b * kT + t0 + tid) * kCP;
#pragma unroll
  for (int c = 0; c < kC; ++c) out[c] = acc[c];
#pragma unroll
  for (int c = kC; c < kCP; ++c) out[c] = 0.f;
}

// e_kernel: bf16 MFMA GEMM (128x128 tile, K=544) + fused tanh/wg epilogue.
// A = [value | conv] converted to bf16 during LDS staging; B = pre-packed Wbf.
constexpr int BM = 128, BN = 128, BK = 32;

__global__ __launch_bounds__(256) void e_kernel(
    const float* __restrict__ value, const float* __restrict__ convT16,
    const short* __restrict__ Wbf, const float* __restrict__ bias,
    const float* __restrict__ w_g, const int* __restrict__ lens,
    float* __restrict__ e_buf) {
  // As: pad row to 40 shorts -> b128 frag reads AND staging writes conflict-free
  __shared__ short As[BM][40];
  __shared__ short Bs[BM * BK];   // unpadded: global_load_lds lane-order layout

  int tid = threadIdx.x;
  // XCD swizzle: 4 n-blocks of one m-tile on the same XCD (L2 A-reuse)
  int L    = blockIdx.x;
  int xcd  = L & 7;
  int slot = L >> 3;
  int bn   = slot & 3;            // 4 n-blocks (N=512)
  int mt   = xcd * 64 + (slot >> 2);   // 512 m-tiles
  int b  = mt >> 5;               // 32 m-tiles per batch row
  int t0 = (mt & 31) * BM;
  if (t0 >= lens[b]) return;      // masked tile
  int n0 = bn * BN;

  int w    = tid >> 6;            // wave 0..3
  int lane = tid & 63;
  int nl   = lane & 15;
  int quad = lane >> 4;
  int wm = w >> 1, wn = w & 1;    // 2x2 waves over 128x128

  // A staging: thread -> (row, khalf): 16 fp32 -> 16 bf16 -> 2x ds_write_b128
  int srow = tid >> 1, skh = tid & 1;
  const float* aptr = value + ((size_t)(b * kT + t0) + srow) * kD + skh * 16;
  const float* cptr = convT16 + ((size_t)(b * kT + t0) + srow) * kCP;

  // B staging: wave w covers rows [w*32, w*32+32), 2 glds of 16B/lane
  const short* bptr0 = Wbf + (size_t)(n0 + w * 32 + (lane >> 2)) * kKP + (lane & 3) * 8;
  const short* bptr1 = bptr0 + (size_t)16 * kKP;
  short* bs0 = &Bs[(w * 32) * BK];
  short* bs1 = &Bs[(w * 32 + 16) * BK];

  float4_t acc[4][4] = {};

  for (int kk = 0; kk < 17; ++kk) {
    int k0 = kk * BK;
    __syncthreads();   // prior compute done; LDS safe to overwrite
    glds16(bptr0 + k0, bs0);
    glds16(bptr1 + k0, bs1);
    short av[16];
    if (kk < 16) {
      float4 f0 = *(const float4*)(aptr + k0);
      float4 f1 = *(const float4*)(aptr + k0 + 4);
      float4 f2 = *(const float4*)(aptr + k0 + 8);
      float4 f3 = *(const float4*)(aptr + k0 + 12);
      av[0] = f2bf(f0.x); av[1] = f2bf(f0.y); av[2]  = f2bf(f0.z); av[3]  = f2bf(f0.w);
      av[4] = f2bf(f1.x); av[5] = f2bf(f1.y); av[6]  = f2bf(f1.z); av[7]  = f2bf(f1.w);
      av[8] = f2bf(f2.x); av[9] = f2bf(f2.y); av[10] = f2bf(f2.z); av[11] = f2bf(f2.w);
      av[12] = f2bf(f3.x); av[13] = f2bf(f3.y); av[14] = f2bf(f3.z); av[15] = f2bf(f3.w);
    } else if (skh == 0) {   // last K-step: conv columns (10 real + 6 zero)
      float4 f0 = *(const float4*)(cptr);
      float4 f1 = *(const float4*)(cptr + 4);
      float4 f2 = *(const float4*)(cptr + 8);
      float4 f3 = *(const float4*)(cptr + 12);
      av[0] = f2bf(f0.x); av[1] = f2bf(f0.y); av[2]  = f2bf(f0.z); av[3]  = f2bf(f0.w);
      av[4] = f2bf(f1.x); av[5] = f2bf(f1.y); av[6]  = f2bf(f1.z); av[7]  = f2bf(f1.w);
      av[8] = f2bf(f2.x); av[9] = f2bf(f2.y); av[10] = f2bf(f2.z); av[11] = f2bf(f2.w);
      av[12] = f2bf(f3.x); av[13] = f2bf(f3.y); av[14] = f2bf(f3.z); av[15] = f2bf(f3.w);
    } else {
#pragma unroll
      for (int i = 0; i < 16; ++i) av[i] = 0;
    }
    *(short8_t*)(&As[srow][skh * 16])     = *(short8_t*)(&av[0]);
    *(short8_t*)(&As[srow][skh * 16 + 8]) = *(short8_t*)(&av[8]);
    __syncthreads();   // drains vmcnt (glds) + lgkmcnt (ds_write)

    short8_t a_frag[4], b_frag[4];
#pragma unroll
    for (int i = 0; i < 4; ++i)
      a_frag[i] = *(const short8_t*)(&As[wm * 64 + i * 16 + nl][quad * 8]);
#pragma unroll
    for (int j = 0; j < 4; ++j)
      b_frag[j] = *(const short8_t*)(&Bs[(wn * 64 + j * 16 + nl) * BK + quad * 8]);
#pragma unroll
    for (int i = 0; i < 4; ++i)
#pragma unroll
      for (int j = 0; j < 4; ++j)
        acc[i][j] = __builtin_amdgcn_mfma_f32_16x16x32_bf16(
            a_frag[i], b_frag[j], acc[i][j], 0, 0, 0);
  }

  // epilogue: e[t] += sum_d wg[d]*tanh(acc + bias[b,d])
  float bias_r[4], wg_r[4];
#pragma unroll
  for (int j = 0; j < 4; ++j) {
    int d = n0 + wn * 64 + j * 16 + nl;
    bias_r[j] = bias[b * kD + d];
    wg_r[j]   = w_g[d];
  }
#pragma unroll
  for (int i = 0; i < 4; ++i) {
#pragma unroll
    for (int r = 0; r < 4; ++r) {
      float s = 0.f;
#pragma unroll
      for (int j = 0; j < 4; ++j)
        s += wg_r[j] * tanh_fast(acc[i][j][r] + bias_r[j]);
      // reduce over the 16 lanes sharing this t (d-groups)
      s += __shfl_xor(s, 1, 64);
      s += __shfl_xor(s, 2, 64);
      s += __shfl_xor(s, 4, 64);
      s += __shfl_xor(s, 8, 64);
      if (nl == 0) {
        int t = t0 + wm * 64 + i * 16 + quad * 4 + r;
        atomicAdd(&e_buf[(size_t)b * kT + t], s);
      }
    }
  }
}

// masked, sharpened softmax (b_g dropped: shift-invariant)
__global__ void softmax_kernel(const float* __restrict__ e_buf,
                               const int* __restrict__ lens,
                               float* __restrict__ att) {
  __shared__ float sred[256];
  int b = blockIdx.x, tid = threadIdx.x;
  int len = lens[b];
  const float* e = e_buf + (size_t)b * kT;
  float m = -3.0e38f;
  for (int t = tid; t < len; t += 256) m = fmaxf(m, e[t]);
  sred[tid] = m; __syncthreads();
  for (int s = 128; s > 0; s >>= 1) {
    if (tid < s) sred[tid] = fmaxf(sred[tid], sred[tid + s]);
    __syncthreads();
  }
  m = sred[0]; __syncthreads();
  float sum = 0.f;
  for (int t = tid; t < len; t += 256) sum += __expf(2.0f * (e[t] - m));
  sred[tid] = sum; __syncthreads();
  for (int s = 128; s > 0; s >>= 1) {
    if (tid < s) sred[tid] += sred[tid + s];
    __syncthreads();
  }
  float inv = 1.0f / sred[0];
  for (int t = tid; t < kT; t += 256)
    att[(size_t)b * kT + t] = (t < len) ? __expf(2.0f * (e[t] - m)) * inv : 0.0f;
}

// context[b,d] = sum_t value[b,t,d]*att[b,t]; float4/lane coalesced
__global__ void context_kernel(const float* __restrict__ value,
                               const float* __restrict__ att,
                               const int* __restrict__ lens,
                               float* __restrict__ ctx) {
  int b = blockIdx.y;
  int len = lens[b];
  int t0 = blockIdx.x * 128;
  if (t0 >= len) return;
  int tid = threadIdx.x;
  int d4 = (tid & 127) * 4;
  int th = tid >> 7;                       // 2 t-streams
  int tb = t0 + th * 64;
  int tmax = min(64, len - tb);
  const float* ap = att + (size_t)b * kT + tb;
  const float* vp = value + ((size_t)(b * kT) + tb) * kD + d4;
  float4 a = {0.f, 0.f, 0.f, 0.f};
  for (int t = 0; t < tmax; ++t) {
    float wt = ap[t];
    float4 v = *(const float4*)(vp + (size_t)t * kD);
    a.x += wt * v.x; a.y += wt * v.y; a.z += wt * v.z; a.w += wt * v.w;
  }
  if (tmax > 0) {
    atomicAdd(&ctx[b * kD + d4],     a.x);
    atomicAdd(&ctx[b * kD + d4 + 1], a.y);
    atomicAdd(&ctx[b * kD + d4 + 2], a.z);
    atomicAdd(&ctx[b * kD + d4 + 3], a.w);
  }
}

extern "C" void kernel_launch(void* const* d_in, const int* in_sizes, int n_in,
                              void* d_out, int out_size, void* d_ws, size_t ws_size,
                              hipStream_t stream) {
  const float* value    = (const float*)d_in[0];
  const float* query    = (const float*)d_in[1];
  const int*   lens     = (const int*)  d_in[2];
  const float* att_prev = (const float*)d_in[3];
  const float* W_enc    = (const float*)d_in[4];
  const float* b_enc    = (const float*)d_in[5];
  const float* W_dec    = (const float*)d_in[6];
  const float* W_att    = (const float*)d_in[7];
  const float* W_conv   = (const float*)d_in[8];
  const float* w_g      = (const float*)d_in[9];
  // d_in[10] = b_g : unused (softmax shift-invariant)

  float* ws      = (float*)d_ws;
  float* e_buf   = ws;                                   // kB*kT            (256 KB)
  float* convT16 = ws + (size_t)kB * kT;                 // kB*kT*16 fp32    (4 MB)
  float* bias    = convT16 + (size_t)kB * kT * kCP;      // kB*kD            (32 KB)
  short* Wbf     = (short*)(bias + (size_t)kB * kD);     // kD*kKP bf16      (557 KB)
  float* ctx = (float*)d_out;
  float* att = ctx + (size_t)kB * kD;

  hipMemsetAsync(e_buf, 0, (size_t)kB * kT * sizeof(float), stream);
  hipMemsetAsync(ctx,   0, (size_t)kB * kD * sizeof(float), stream);

  dec_bias_kernel<<<kB * kD / 4, 256, 0, stream>>>(query, W_dec, b_enc, bias);
  pack_w_kernel<<<kD, 256, 0, stream>>>(W_enc, W_att, Wbf);
  conv_kernel<<<dim3(kT / 256, kB), 256, 0, stream>>>(att_prev, W_conv, convT16);
  e_kernel<<<2048, 256, 0, stream>>>(value, convT16, Wbf, bias, w_g, lens, e_buf);
  softmax_kernel<<<kB, 256, 0, stream>>>(e_buf, lens, att);
  context_kernel<<<dim3(kT / 128, kB), 256, 0, stream>>>(value, att, lens, ctx);
}